// Round 3
// baseline (325.766 us; speedup 1.0000x reference)
//
#include <hip/hip_runtime.h>

typedef __attribute__((ext_vector_type(8))) short          bf16x8;
typedef __attribute__((ext_vector_type(8))) unsigned short u16x8;
typedef __attribute__((ext_vector_type(4))) unsigned short u16x4;
typedef __attribute__((ext_vector_type(4))) float          f32x4;
typedef __attribute__((ext_vector_type(4))) unsigned int   u32x4;

union U8 { u16x8 u; bf16x8 b; u32x4 w; };
union U4 { u16x4 u; unsigned w[2]; };

__device__ __forceinline__ unsigned short f2bf(float f){
  unsigned u = __float_as_uint(f);
  return (unsigned short)((u + 0x7fffu + ((u >> 16) & 1u)) >> 16);
}
// pack two floats to bf16x2 (round-half-up): lo->low16, hi->high16. exact 0 preserved.
__device__ __forceinline__ unsigned pack_bf16(float lo, float hi){
  unsigned a = __float_as_uint(hi) + 0x8000u;
  unsigned b = __float_as_uint(lo) + 0x8000u;
  return __builtin_amdgcn_perm(a, b, 0x07060302u);
}
// max-pair -> packed bf16 (RNE) -> halfword mask (0xFFFF/0x0000 halves).
__device__ __forceinline__ unsigned maskpack(float e0, float e1, unsigned m){
  unsigned r;
  asm("v_cvt_pk_bf16_f32 %0, %1, %2" : "=v"(r) : "v"(e0), "v"(e1));
  return r & m;
}

#define NN  1024
#define FIN 256
#define NH  8
#define FO  64

// ---------------------------------------------------------------------------
// Stage 0: wfrag = w in MFMA-B-frag layout; Abits = bit-packed A;
//          out = bias*mz (pre-init for stageB's atomic head-merge).
// grid 1024 x 256
// ---------------------------------------------------------------------------
__global__ __launch_bounds__(256) void stage0(
    const float* __restrict__ w, const int* __restrict__ A,
    const float* __restrict__ bias, const float* __restrict__ mz,
    unsigned short* __restrict__ wfrag, unsigned long long* __restrict__ Abits,
    float* __restrict__ out)
{
  const int tid = blockIdx.x * 256 + threadIdx.x;    // 262144 threads
  if (tid < 16384){
    const int lane = tid & 63, ss = (tid >> 6) & 3, kc = (tid >> 8) & 7, h = tid >> 11;
    const int o = 16 * ss + (lane & 15);
    const int f = kc * 32 + (lane >> 4) * 8;
    u16x8 r;
    #pragma unroll
    for (int j = 0; j < 8; j++) r[j] = f2bf(w[(h * FIN + f + j) * FO + o]);
    *(u16x8*)(wfrag + tid * 8) = r;
  }
  #pragma unroll
  for (int k = 0; k < 2; k++){                       // out = bias*mz
    const int i = tid + k * 262144;
    out[i] = bias[i & 63] * mz[i >> 6];
  }
  for (int i = tid; i < 8388608; i += 262144){       // adjacency bit-pack
    unsigned long long m = __ballot(A[i] > 0);
    if ((threadIdx.x & 63) == 0) Abits[i >> 6] = m;
  }
}

// ---------------------------------------------------------------------------
// Stage A: recx built in LDS per 16-row tile; h = recx @ w (MFMA);
// panel stores hT[b,h,mtile,o,32] + exp tables (R = exp(0.8 s), Ed, Ed2).
// grid (64 tiles(16 rows), 8 b) = 512 blocks, block 512 (8 waves = 8 heads).
// ---------------------------------------------------------------------------
__global__ __launch_bounds__(512, 4) void stageA(
    const float* __restrict__ x, const float* __restrict__ e_at,
    const float* __restrict__ Np, const unsigned short* __restrict__ wfrag,
    const float* __restrict__ a_src, const float* __restrict__ a_dst,
    unsigned short* __restrict__ hT,
    float* __restrict__ Rt, float* __restrict__ expd, float* __restrict__ expd2)
{
  __shared__ unsigned short rex[16 * 264];   // 16 rows x 256 f, pad 264
  const int t = threadIdx.x;
  const int n0 = blockIdx.x * 16, b = blockIdx.y;

  {                                          // cooperative recx tile build
    const int row = t >> 5, f0 = (t & 31) * 8;
    const int nrow = n0 + row;
    const float* ep = e_at + (b * NN + nrow) * FIN + f0;
    const float* qp = Np + nrow * FIN + f0;
    const float* xp = x + b * FIN + f0;
    f32x4 e0 = *(const f32x4*)ep, e1 = *(const f32x4*)(ep + 4);
    f32x4 q0 = *(const f32x4*)qp, q1 = *(const f32x4*)(qp + 4);
    f32x4 x0 = *(const f32x4*)xp, x1 = *(const f32x4*)(xp + 4);
    u16x8 r;
    #pragma unroll
    for (int j = 0; j < 4; j++){
      r[j]     = f2bf(e0[j] * q0[j] * x0[j]);
      r[j + 4] = f2bf(e1[j] * q1[j] * x1[j]);
    }
    *(u16x8*)(rex + row * 264 + f0) = r;
  }
  __syncthreads();

  const int h = t >> 6, lane = t & 63, quad = lane >> 4, l15 = lane & 15;
  const unsigned short* wf = wfrag + h * 16384 + lane * 8;

  f32x4 acc[4] = {};
  #pragma unroll
  for (int kc = 0; kc < 8; kc++){
    U8 a0, bf[4];
    a0.u = *(const u16x8*)(rex + l15 * 264 + kc * 32 + quad * 8);
    #pragma unroll
    for (int ss = 0; ss < 4; ss++) bf[ss].u = *(const u16x8*)(wf + (kc * 4 + ss) * 512);
    #pragma unroll
    for (int ss = 0; ss < 4; ss++)
      acc[ss] = __builtin_amdgcn_mfma_f32_16x16x32_bf16(a0.b, bf[ss].b, acc[ss], 0, 0, 0);
  }

  // panel store: [b,h,mtile,o(64),m(32)], C/D row(n)=quad*4+i, col(o)=16ss+l15
  {
    const int mtile = blockIdx.x >> 1, moff = (blockIdx.x & 1) * 16;
    unsigned short* pan = hT + (size_t)(((b * NH + h) * 32 + mtile) * 64) * 32;
    #pragma unroll
    for (int ss = 0; ss < 4; ss++){
      U4 v;
      v.w[0] = pack_bf16(acc[ss][0], acc[ss][1]);
      v.w[1] = pack_bf16(acc[ss][2], acc[ss][3]);
      *(u16x4*)(pan + (16 * ss + l15) * 32 + moff + quad * 4) = v.u;
    }
  }

  // s/d reductions -> exp tables (R = exp(0.8 s): row factor exp(0.2 s) cancels
  // in softmax, so P' = max(R*Ed, Ed2) gives identical attention weights)
  float as4[4], ad4[4];
  #pragma unroll
  for (int ss = 0; ss < 4; ss++){
    as4[ss] = a_src[h * FO + 16 * ss + l15];
    ad4[ss] = a_dst[h * FO + 16 * ss + l15];
  }
  #pragma unroll
  for (int i = 0; i < 4; i++){
    float ps = 0.f, pd = 0.f;
    #pragma unroll
    for (int ss = 0; ss < 4; ss++){ ps += acc[ss][i] * as4[ss]; pd += acc[ss][i] * ad4[ss]; }
    #pragma unroll
    for (int off = 1; off < 16; off <<= 1){
      ps += __shfl_xor(ps, off);
      pd += __shfl_xor(pd, off);
    }
    if (l15 == 0){
      const int idx = (b * NH + h) * NN + n0 + quad * 4 + i;
      Rt[idx]    = __expf(0.8f * ps);
      expd[idx]  = __expf(pd);
      expd2[idx] = __expf(0.2f * pd);
    }
  }
}

// ---------------------------------------------------------------------------
// Stage B: fused masked-softmax aggregation, occupancy-first.
// 2048 flat blocks of 256 thr; block = 1 head x 32 rows; 4 waves = 4 m-quarters
// (8 iters each, 2 row-groups in-register -> inner loop identical to R2).
// LDS ~8.7 KB + VGPR<=64 -> __launch_bounds__(256,8): 8 blocks/CU = 32 waves/CU
// (2x R2's wave pool; R2 was latency-bound at 28.8% occupancy).
// XCD swizzle: b = fid&7 -> each XCD owns one b (panels 1MB + Abits 128KB in L2,
// proven in R2: FETCH 43->5MB). Masks read straight from L2 Abits (1-deep
// prefetch) - no LDS mask staging. m-quarters + denominators merge in LDS
// (tables reused as merge buffer after the loop); one normalized atomicAdd
// per element per head-block (4.2M atomics vs R2's 8.4M).
// ---------------------------------------------------------------------------
__global__ __launch_bounds__(256, 8) void stageB(
    const unsigned* __restrict__ Aw,
    const unsigned short* __restrict__ hT,
    const float* __restrict__ Rt,
    const float* __restrict__ expd, const float* __restrict__ expd2,
    const float* __restrict__ mz, float* __restrict__ out)
{
  __shared__ float tab[2112];                    // ed[0..1023] | e2[1024..2047];
                                                 // reused after loop as merge[32][65]
  __shared__ __align__(8) unsigned lut[16][2];   // nibble -> 2 halfword masks
  __shared__ float l_l[32];                      // per-row denominators

  // decode: XCD = fid&7 = b
  const int fid = blockIdx.x;
  const int b = fid & 7, h = (fid >> 3) & 7, nt = fid >> 6;  // nt in [0,32)
  const int n0 = nt * 32;

  const int t = threadIdx.x;                     // 256
  const int w = t >> 6, lane = t & 63, quad = lane >> 4, l15 = lane & 15;
  const int mh = w;                              // m-quarter

  if (t < 32) l_l[t] = 0.f;
  if (t < 16){
    lut[t][0] = (t & 1 ? 0xFFFFu : 0u) | (t & 2 ? 0xFFFF0000u : 0u);
    lut[t][1] = (t & 4 ? 0xFFFFu : 0u) | (t & 8 ? 0xFFFF0000u : 0u);
  }
  {                                      // exp-table preload (1 head, coalesced)
    const float* s1 = expd  + (b * NH + h) * NN;
    const float* s2 = expd2 + (b * NH + h) * NN;
    *(f32x4*)(tab + t * 4)        = *(const f32x4*)(s1 + t * 4);
    *(f32x4*)(tab + 1024 + t * 4) = *(const f32x4*)(s2 + t * 4);
  }
  __syncthreads();

  const int hb = (b * NH + h) * NN;
  const float Rv0 = Rt[hb + n0 + l15];
  const float Rv1 = Rt[hb + n0 + 16 + l15];
  const unsigned short* pb = hT + (size_t)(b * NH + h) * 65536 + l15 * 32 + quad * 8;
  const float* edh = tab + quad * 8;
  const float* e2h = tab + 1024 + quad * 8;
  const unsigned* awp = Aw + (b * NN + n0) * 32;
  const int c0 = mh * 8;
  const int qs = quad * 8;

  U8 pan[4];
  #pragma unroll
  for (int ss = 0; ss < 4; ss++)
    pan[ss].u = *(const u16x8*)(pb + (size_t)c0 * 2048 + ss * 512);
  unsigned mw0 = awp[l15 * 32 + c0];
  unsigned mw1 = awp[(16 + l15) * 32 + c0];

  U8 ones;                               // bf16 1.0 B-frag for row sums
  #pragma unroll
  for (int j = 0; j < 8; j++) ones.u[j] = 0x3F80;

  f32x4 acc0[4] = {}, acc1[4] = {};
  f32x4 accl0 = {}, accl1 = {};

  for (int cc = 0; cc < 8; cc++){
    const int c = c0 + cc;
    // expand bit masks via LUT (mask words prefetched last iter)
    const unsigned am0 = (mw0 >> qs) & 0xFF;
    const unsigned am1 = (mw1 >> qs) & 0xFF;
    const uint2 la0 = *(const uint2*)&lut[am0 & 15][0];
    const uint2 lb0 = *(const uint2*)&lut[(am0 >> 4) & 15][0];
    const uint2 la1 = *(const uint2*)&lut[am1 & 15][0];
    const uint2 lb1 = *(const uint2*)&lut[(am1 >> 4) & 15][0];
    if (cc + 1 < 8){                     // mask prefetch from L2 (Abits)
      mw0 = awp[l15 * 32 + c + 1];
      mw1 = awp[(16 + l15) * 32 + c + 1];
    }
    // shared column factors (broadcast LDS reads, conflict-free)
    const f32x4 d01 = *(const f32x4*)(edh + c * 32);
    const f32x4 d23 = *(const f32x4*)(edh + c * 32 + 4);
    const f32x4 g01 = *(const f32x4*)(e2h + c * 32);
    const f32x4 g23 = *(const f32x4*)(e2h + c * 32 + 4);
    // P for row-group 0
    {
      const f32x4 p01 = Rv0 * d01, p23 = Rv0 * d23;
      U8 p;
      p.w[0] = maskpack(fmaxf(p01[0], g01[0]), fmaxf(p01[1], g01[1]), la0.x);
      p.w[1] = maskpack(fmaxf(p01[2], g01[2]), fmaxf(p01[3], g01[3]), la0.y);
      p.w[2] = maskpack(fmaxf(p23[0], g23[0]), fmaxf(p23[1], g23[1]), lb0.x);
      p.w[3] = maskpack(fmaxf(p23[2], g23[2]), fmaxf(p23[3], g23[3]), lb0.y);
      #pragma unroll
      for (int ss = 0; ss < 4; ss++)
        acc0[ss] = __builtin_amdgcn_mfma_f32_16x16x32_bf16(p.b, pan[ss].b, acc0[ss], 0, 0, 0);
      accl0 = __builtin_amdgcn_mfma_f32_16x16x32_bf16(p.b, ones.b, accl0, 0, 0, 0);
    }
    // P for row-group 1 (same pan frags -> panel traffic halved)
    {
      const f32x4 p01 = Rv1 * d01, p23 = Rv1 * d23;
      U8 p;
      p.w[0] = maskpack(fmaxf(p01[0], g01[0]), fmaxf(p01[1], g01[1]), la1.x);
      p.w[1] = maskpack(fmaxf(p01[2], g01[2]), fmaxf(p01[3], g01[3]), la1.y);
      p.w[2] = maskpack(fmaxf(p23[0], g23[0]), fmaxf(p23[1], g23[1]), lb1.x);
      p.w[3] = maskpack(fmaxf(p23[2], g23[2]), fmaxf(p23[3], g23[3]), lb1.y);
      #pragma unroll
      for (int ss = 0; ss < 4; ss++)
        acc1[ss] = __builtin_amdgcn_mfma_f32_16x16x32_bf16(p.b, pan[ss].b, acc1[ss], 0, 0, 0);
      accl1 = __builtin_amdgcn_mfma_f32_16x16x32_bf16(p.b, ones.b, accl1, 0, 0, 0);
    }
    if (cc + 1 < 8){                     // pan prefetch, 1-deep (back of chain)
      #pragma unroll
      for (int ss = 0; ss < 4; ss++)
        pan[ss].u = *(const u16x8*)(pb + (size_t)(c + 1) * 2048 + ss * 512);
    }
  }

  // accl[i] = row partial denominator over this wave's m-quarter (replicated
  // over l15 cols); merge 4 waves via LDS atomics
  if (l15 == 0){
    #pragma unroll
    for (int i = 0; i < 4; i++){
      atomicAdd(&l_l[quad * 4 + i], accl0[i]);
      atomicAdd(&l_l[16 + quad * 4 + i], accl1[i]);
    }
  }
  __syncthreads();                       // l_l done; all waves out of the loop

  // reuse tab as merge[32][65] (stride 65 kills 4-way bank conflict on adds)
  for (int i = t; i < 2080; i += 256) tab[i] = 0.f;
  __syncthreads();

  #pragma unroll
  for (int i = 0; i < 4; i++){
    const int r0 = quad * 4 + i;
    const float ia = 1.0f / l_l[r0];
    const float ib = 1.0f / l_l[16 + r0];
    #pragma unroll
    for (int ss = 0; ss < 4; ss++){
      atomicAdd(&tab[r0 * 65 + ss * 16 + l15], acc0[ss][i] * ia);
      atomicAdd(&tab[(16 + r0) * 65 + ss * 16 + l15], acc1[ss][i] * ib);
    }
  }
  __syncthreads();

  // one normalized atomic per element per head-block (1/8 + mz folded);
  // thread t owns row t>>3, cols (t&7)*8..+7 (coalesced)
  {
    const int r = t >> 3;
    const float sc = 0.125f * mz[b * NN + n0 + r];
    float* op = out + (size_t)(b * NN + n0 + r) * FO + (t & 7) * 8;
    const float* mrg = tab + r * 65 + (t & 7) * 8;
    #pragma unroll
    for (int k = 0; k < 8; k++) atomicAdd(op + k, mrg[k] * sc);
  }
}

extern "C" void kernel_launch(void* const* d_in, const int* in_sizes, int n_in,
                              void* d_out, int out_size, void* d_ws, size_t ws_size,
                              hipStream_t stream)
{
  (void)in_sizes; (void)n_in; (void)out_size; (void)ws_size;
  const float* x    = (const float*)d_in[0];
  const int*   A    = (const int*)d_in[1];
  const float* mz   = (const float*)d_in[2];
  const float* e_at = (const float*)d_in[4];
  const float* Np   = (const float*)d_in[5];
  const float* w    = (const float*)d_in[6];
  const float* asrc = (const float*)d_in[7];
  const float* adst = (const float*)d_in[8];
  const float* bias = (const float*)d_in[9];
  float* out = (float*)d_out;

  char* ws = (char*)d_ws;
  unsigned short* wfrag = (unsigned short*)ws;                     // 256 KB
  unsigned short* hT    = (unsigned short*)(ws + 262144);          // 8 MB
  float* Rt    = (float*)(ws + 8650752);                           // 256 KB
  float* expd  = (float*)(ws + 8912896);                           // 256 KB
  float* expd2 = (float*)(ws + 9175040);                           // 256 KB
  unsigned long long* Abits = (unsigned long long*)(ws + 9437184); // 1 MB

  stage0<<<dim3(1024), dim3(256), 0, stream>>>(w, A, bias, mz, wfrag, Abits, out);
  stageA<<<dim3(64, 8), dim3(512), 0, stream>>>(x, e_at, Np, wfrag, asrc, adst,
                                                hT, Rt, expd, expd2);
  stageB<<<dim3(2048), dim3(256), 0, stream>>>((const unsigned*)Abits, hT,
                                               Rt, expd, expd2, mz, out);
}

// Round 4
// 153.016 us; speedup vs baseline: 2.1290x; 2.1290x over previous
//
#include <hip/hip_runtime.h>

typedef __attribute__((ext_vector_type(8))) short          bf16x8;
typedef __attribute__((ext_vector_type(8))) unsigned short u16x8;
typedef __attribute__((ext_vector_type(4))) unsigned short u16x4;
typedef __attribute__((ext_vector_type(4))) float          f32x4;
typedef __attribute__((ext_vector_type(4))) unsigned int   u32x4;

union U8 { u16x8 u; bf16x8 b; u32x4 w; };
union U4 { u16x4 u; unsigned w[2]; };

__device__ __forceinline__ unsigned short f2bf(float f){
  unsigned u = __float_as_uint(f);
  return (unsigned short)((u + 0x7fffu + ((u >> 16) & 1u)) >> 16);
}
// pack two floats to bf16x2 (round-half-up): lo->low16, hi->high16. exact 0 preserved.
__device__ __forceinline__ unsigned pack_bf16(float lo, float hi){
  unsigned a = __float_as_uint(hi) + 0x8000u;
  unsigned b = __float_as_uint(lo) + 0x8000u;
  return __builtin_amdgcn_perm(a, b, 0x07060302u);
}
// max-pair -> packed bf16 (RNE) -> halfword mask (0xFFFF/0x0000 halves).
__device__ __forceinline__ unsigned maskpack(float e0, float e1, unsigned m){
  unsigned r;
  asm("v_cvt_pk_bf16_f32 %0, %1, %2" : "=v"(r) : "v"(e0), "v"(e1));
  return r & m;
}

#define NN  1024
#define FIN 256
#define NH  8
#define FO  64

// ---------------------------------------------------------------------------
// Stage 0: wfrag = w in MFMA-B-frag layout; Abits = bit-packed A.
// grid 1024 x 256
// ---------------------------------------------------------------------------
__global__ __launch_bounds__(256) void stage0(
    const float* __restrict__ w, const int* __restrict__ A,
    unsigned short* __restrict__ wfrag, unsigned long long* __restrict__ Abits)
{
  const int tid = blockIdx.x * 256 + threadIdx.x;    // 262144 threads
  if (tid < 16384){
    const int lane = tid & 63, ss = (tid >> 6) & 3, kc = (tid >> 8) & 7, h = tid >> 11;
    const int o = 16 * ss + (lane & 15);
    const int f = kc * 32 + (lane >> 4) * 8;
    u16x8 r;
    #pragma unroll
    for (int j = 0; j < 8; j++) r[j] = f2bf(w[(h * FIN + f + j) * FO + o]);
    *(u16x8*)(wfrag + tid * 8) = r;
  }
  for (int i = tid; i < 8388608; i += 262144){       // adjacency bit-pack
    unsigned long long m = __ballot(A[i] > 0);
    if ((threadIdx.x & 63) == 0) Abits[i >> 6] = m;
  }
}

// ---------------------------------------------------------------------------
// Stage A: recx built in LDS per 16-row tile; h = recx @ w (MFMA);
// panel stores hT[b,h,mtile,o,32] + exp tables (R = exp(0.8 s), Ed, Ed2).
// grid (64 tiles(16 rows), 8 b) = 512 blocks, block 512 (8 waves = 8 heads).
// ---------------------------------------------------------------------------
__global__ __launch_bounds__(512, 4) void stageA(
    const float* __restrict__ x, const float* __restrict__ e_at,
    const float* __restrict__ Np, const unsigned short* __restrict__ wfrag,
    const float* __restrict__ a_src, const float* __restrict__ a_dst,
    unsigned short* __restrict__ hT,
    float* __restrict__ Rt, float* __restrict__ expd, float* __restrict__ expd2)
{
  __shared__ unsigned short rex[16 * 264];   // 16 rows x 256 f, pad 264
  const int t = threadIdx.x;
  const int n0 = blockIdx.x * 16, b = blockIdx.y;

  {                                          // cooperative recx tile build
    const int row = t >> 5, f0 = (t & 31) * 8;
    const int nrow = n0 + row;
    const float* ep = e_at + (b * NN + nrow) * FIN + f0;
    const float* qp = Np + nrow * FIN + f0;
    const float* xp = x + b * FIN + f0;
    f32x4 e0 = *(const f32x4*)ep, e1 = *(const f32x4*)(ep + 4);
    f32x4 q0 = *(const f32x4*)qp, q1 = *(const f32x4*)(qp + 4);
    f32x4 x0 = *(const f32x4*)xp, x1 = *(const f32x4*)(xp + 4);
    u16x8 r;
    #pragma unroll
    for (int j = 0; j < 4; j++){
      r[j]     = f2bf(e0[j] * q0[j] * x0[j]);
      r[j + 4] = f2bf(e1[j] * q1[j] * x1[j]);
    }
    *(u16x8*)(rex + row * 264 + f0) = r;
  }
  __syncthreads();

  const int h = t >> 6, lane = t & 63, quad = lane >> 4, l15 = lane & 15;
  const unsigned short* wf = wfrag + h * 16384 + lane * 8;

  f32x4 acc[4] = {};
  #pragma unroll
  for (int kc = 0; kc < 8; kc++){
    U8 a0, bf[4];
    a0.u = *(const u16x8*)(rex + l15 * 264 + kc * 32 + quad * 8);
    #pragma unroll
    for (int ss = 0; ss < 4; ss++) bf[ss].u = *(const u16x8*)(wf + (kc * 4 + ss) * 512);
    #pragma unroll
    for (int ss = 0; ss < 4; ss++)
      acc[ss] = __builtin_amdgcn_mfma_f32_16x16x32_bf16(a0.b, bf[ss].b, acc[ss], 0, 0, 0);
  }

  // panel store: [b,h,mtile,o(64),m(32)], C/D row(n)=quad*4+i, col(o)=16ss+l15
  {
    const int mtile = blockIdx.x >> 1, moff = (blockIdx.x & 1) * 16;
    unsigned short* pan = hT + (size_t)(((b * NH + h) * 32 + mtile) * 64) * 32;
    #pragma unroll
    for (int ss = 0; ss < 4; ss++){
      U4 v;
      v.w[0] = pack_bf16(acc[ss][0], acc[ss][1]);
      v.w[1] = pack_bf16(acc[ss][2], acc[ss][3]);
      *(u16x4*)(pan + (16 * ss + l15) * 32 + moff + quad * 4) = v.u;
    }
  }

  // s/d reductions -> exp tables (R = exp(0.8 s): row factor exp(0.2 s) cancels
  // in softmax, so P' = max(R*Ed, Ed2) gives identical attention weights)
  float as4[4], ad4[4];
  #pragma unroll
  for (int ss = 0; ss < 4; ss++){
    as4[ss] = a_src[h * FO + 16 * ss + l15];
    ad4[ss] = a_dst[h * FO + 16 * ss + l15];
  }
  #pragma unroll
  for (int i = 0; i < 4; i++){
    float ps = 0.f, pd = 0.f;
    #pragma unroll
    for (int ss = 0; ss < 4; ss++){ ps += acc[ss][i] * as4[ss]; pd += acc[ss][i] * ad4[ss]; }
    #pragma unroll
    for (int off = 1; off < 16; off <<= 1){
      ps += __shfl_xor(ps, off);
      pd += __shfl_xor(pd, off);
    }
    if (l15 == 0){
      const int idx = (b * NH + h) * NN + n0 + quad * 4 + i;
      Rt[idx]    = __expf(0.8f * ps);
      expd[idx]  = __expf(pd);
      expd2[idx] = __expf(0.2f * pd);
    }
  }
}

// ---------------------------------------------------------------------------
// Stage B: fused masked-softmax aggregation, ZERO atomics.
// 1024 flat blocks of 256 thr; block = 1 head x 64 rows; 4 waves =
// 2 row-halves(rw) x 2 m-halves(mh); each wave: 32 rows (2 row-groups
// in-register, R2's proven inner loop) x 512 cols, 16 iters.
// __launch_bounds__(256,4): budget 128 regs/wave (gfx950 unified VGPR+AGPR;
// R3 lesson: (256,8)=64 total forces accumulator spill -> 660MB scratch).
// XCD decode b=fid&7: panels+Abits+tables L2-resident (R2: FETCH 43->5MB).
// m-halves merge through LDS (tab reused after loop; one extra barrier);
// denominators per-wave LDS slots; mh=0 waves normalize in-register and write
// per-head hpart with plain coalesced stores. Head-merge deferred to stageC.
// ---------------------------------------------------------------------------
__global__ __launch_bounds__(256, 4) void stageB(
    const unsigned* __restrict__ Aw,
    const unsigned short* __restrict__ hT,
    const float* __restrict__ Rt,
    const float* __restrict__ expd, const float* __restrict__ expd2,
    float* __restrict__ hpart)
{
  // phase 1: smem[0..1023]=Ed, [1024..2047]=Ed2 (this head)
  // phase 2: smem[0..4159]=merge[64][65], smem[4160..4287]=den[2mh][64]
  __shared__ float smem[4288];
  __shared__ __align__(8) unsigned lut[16][2];   // nibble -> 2 halfword masks

  const int fid = blockIdx.x;
  const int b = fid & 7, h = (fid >> 3) & 7, rt = fid >> 6;  // rt in [0,16)
  const int n0 = rt * 64;

  const int t = threadIdx.x;                     // 256
  const int w = t >> 6, lane = t & 63, quad = lane >> 4, l15 = lane & 15;
  const int rw = w & 1, mh = w >> 1;
  const int nb = n0 + rw * 32;                   // wave's 32-row base

  if (t < 16){
    lut[t][0] = (t & 1 ? 0xFFFFu : 0u) | (t & 2 ? 0xFFFF0000u : 0u);
    lut[t][1] = (t & 4 ? 0xFFFFu : 0u) | (t & 8 ? 0xFFFF0000u : 0u);
  }
  {                                      // exp-table preload (1 head, coalesced)
    const float* s1 = expd  + (b * NH + h) * NN;
    const float* s2 = expd2 + (b * NH + h) * NN;
    *(f32x4*)(smem + t * 4)        = *(const f32x4*)(s1 + t * 4);
    *(f32x4*)(smem + 1024 + t * 4) = *(const f32x4*)(s2 + t * 4);
  }
  __syncthreads();

  const int hb = (b * NH + h) * NN;
  const float Rv0 = Rt[hb + nb + l15];
  const float Rv1 = Rt[hb + nb + 16 + l15];
  const unsigned short* pb = hT + (size_t)(b * NH + h) * 65536 + l15 * 32 + quad * 8;
  const float* edh = smem + quad * 8;
  const float* e2h = smem + 1024 + quad * 8;
  const unsigned* awp = Aw + (b * NN + nb) * 32;
  const int c0 = mh * 16;
  const int qs = quad * 8;

  U8 pan[4];
  #pragma unroll
  for (int ss = 0; ss < 4; ss++)
    pan[ss].u = *(const u16x8*)(pb + (size_t)c0 * 2048 + ss * 512);
  unsigned mw0 = awp[l15 * 32 + c0];
  unsigned mw1 = awp[(16 + l15) * 32 + c0];

  U8 ones;                               // bf16 1.0 B-frag for row sums
  #pragma unroll
  for (int j = 0; j < 8; j++) ones.u[j] = 0x3F80;

  f32x4 acc0[4] = {}, acc1[4] = {};
  f32x4 accl0 = {}, accl1 = {};

  for (int cc = 0; cc < 16; cc++){
    const int c = c0 + cc;
    // expand bit masks via LUT (mask words prefetched last iter)
    const unsigned am0 = (mw0 >> qs) & 0xFF;
    const unsigned am1 = (mw1 >> qs) & 0xFF;
    const uint2 la0 = *(const uint2*)&lut[am0 & 15][0];
    const uint2 lb0 = *(const uint2*)&lut[(am0 >> 4) & 15][0];
    const uint2 la1 = *(const uint2*)&lut[am1 & 15][0];
    const uint2 lb1 = *(const uint2*)&lut[(am1 >> 4) & 15][0];
    if (cc + 1 < 16){                    // mask prefetch from L2 (Abits)
      mw0 = awp[l15 * 32 + c + 1];
      mw1 = awp[(16 + l15) * 32 + c + 1];
    }
    // shared column factors (broadcast LDS reads, conflict-free)
    const f32x4 d01 = *(const f32x4*)(edh + c * 32);
    const f32x4 d23 = *(const f32x4*)(edh + c * 32 + 4);
    const f32x4 g01 = *(const f32x4*)(e2h + c * 32);
    const f32x4 g23 = *(const f32x4*)(e2h + c * 32 + 4);
    // P for row-group 0
    {
      const f32x4 p01 = Rv0 * d01, p23 = Rv0 * d23;
      U8 p;
      p.w[0] = maskpack(fmaxf(p01[0], g01[0]), fmaxf(p01[1], g01[1]), la0.x);
      p.w[1] = maskpack(fmaxf(p01[2], g01[2]), fmaxf(p01[3], g01[3]), la0.y);
      p.w[2] = maskpack(fmaxf(p23[0], g23[0]), fmaxf(p23[1], g23[1]), lb0.x);
      p.w[3] = maskpack(fmaxf(p23[2], g23[2]), fmaxf(p23[3], g23[3]), lb0.y);
      #pragma unroll
      for (int ss = 0; ss < 4; ss++)
        acc0[ss] = __builtin_amdgcn_mfma_f32_16x16x32_bf16(p.b, pan[ss].b, acc0[ss], 0, 0, 0);
      accl0 = __builtin_amdgcn_mfma_f32_16x16x32_bf16(p.b, ones.b, accl0, 0, 0, 0);
    }
    // P for row-group 1 (same pan frags -> panel traffic halved)
    {
      const f32x4 p01 = Rv1 * d01, p23 = Rv1 * d23;
      U8 p;
      p.w[0] = maskpack(fmaxf(p01[0], g01[0]), fmaxf(p01[1], g01[1]), la1.x);
      p.w[1] = maskpack(fmaxf(p01[2], g01[2]), fmaxf(p01[3], g01[3]), la1.y);
      p.w[2] = maskpack(fmaxf(p23[0], g23[0]), fmaxf(p23[1], g23[1]), lb1.x);
      p.w[3] = maskpack(fmaxf(p23[2], g23[2]), fmaxf(p23[3], g23[3]), lb1.y);
      #pragma unroll
      for (int ss = 0; ss < 4; ss++)
        acc1[ss] = __builtin_amdgcn_mfma_f32_16x16x32_bf16(p.b, pan[ss].b, acc1[ss], 0, 0, 0);
      accl1 = __builtin_amdgcn_mfma_f32_16x16x32_bf16(p.b, ones.b, accl1, 0, 0, 0);
    }
    if (cc + 1 < 16){                    // pan prefetch, 1-deep (back of chain)
      #pragma unroll
      for (int ss = 0; ss < 4; ss++)
        pan[ss].u = *(const u16x8*)(pb + (size_t)(c + 1) * 2048 + ss * 512);
    }
  }

  __syncthreads();                       // tab dead; smem becomes merge buffer

  // denominators: accl[i] = complete row sum over this wave's m-half,
  // replicated over l15. Distinct (mh,rw,row) slots -> no atomics.
  float* den = smem + 4160;
  if (l15 == 0){
    #pragma unroll
    for (int i = 0; i < 4; i++){
      den[mh * 64 + rw * 32 + quad * 4 + i]      = accl0[i];
      den[mh * 64 + rw * 32 + 16 + quad * 4 + i] = accl1[i];
    }
  }
  // mh=1 waves park their numerators in merge[64][65]
  if (mh == 1){
    #pragma unroll
    for (int i = 0; i < 4; i++){
      const int r0 = rw * 32 + quad * 4 + i;
      #pragma unroll
      for (int ss = 0; ss < 4; ss++){
        smem[r0 * 65 + ss * 16 + l15]        = acc0[ss][i];
        smem[(r0 + 16) * 65 + ss * 16 + l15] = acc1[ss][i];
      }
    }
  }
  __syncthreads();

  // mh=0 waves: add halves, normalize, plain coalesced store to hpart
  if (mh == 0){
    float* hp = hpart + ((size_t)(b * NH + h) * NN + nb) * FO;
    #pragma unroll
    for (int i = 0; i < 4; i++){
      const int r = quad * 4 + i;
      const float ia = 1.0f / (den[rw * 32 + r] + den[64 + rw * 32 + r]);
      const float ib = 1.0f / (den[rw * 32 + 16 + r] + den[64 + rw * 32 + 16 + r]);
      #pragma unroll
      for (int ss = 0; ss < 4; ss++){
        hp[(size_t)r * FO + ss * 16 + l15] =
            (acc0[ss][i] + smem[(rw * 32 + r) * 65 + ss * 16 + l15]) * ia;
        hp[(size_t)(16 + r) * FO + ss * 16 + l15] =
            (acc1[ss][i] + smem[(rw * 32 + 16 + r) * 65 + ss * 16 + l15]) * ib;
      }
    }
  }
}

// ---------------------------------------------------------------------------
// Stage C: head mean + bias + mask. out = (0.125*sum_h hpart + bias) * mz.
// 16.8 MB streamed reads, 2 MB writes. grid 512 x 256, 4 outputs/thread.
// ---------------------------------------------------------------------------
__global__ __launch_bounds__(256) void stageC(
    const float* __restrict__ hpart, const float* __restrict__ bias,
    const float* __restrict__ mz, float* __restrict__ out)
{
  const int tid = blockIdx.x * 256 + threadIdx.x;    // 131072 threads
  const int o4 = (tid & 15) * 4;
  const int n  = (tid >> 4) & 1023;
  const int b  = tid >> 14;
  const size_t nf = (size_t)n * FO + o4;
  f32x4 s = {};
  #pragma unroll
  for (int h = 0; h < NH; h++)
    s += *(const f32x4*)(hpart + (size_t)(b * NH + h) * NN * FO + nf);
  const f32x4 bv = *(const f32x4*)(bias + o4);
  const float m = mz[b * NN + n];
  f32x4 r;
  #pragma unroll
  for (int j = 0; j < 4; j++) r[j] = (0.125f * s[j] + bv[j]) * m;
  *(f32x4*)(out + (size_t)b * NN * FO + nf) = r;
}

extern "C" void kernel_launch(void* const* d_in, const int* in_sizes, int n_in,
                              void* d_out, int out_size, void* d_ws, size_t ws_size,
                              hipStream_t stream)
{
  (void)in_sizes; (void)n_in; (void)out_size; (void)ws_size;
  const float* x    = (const float*)d_in[0];
  const int*   A    = (const int*)d_in[1];
  const float* mz   = (const float*)d_in[2];
  const float* e_at = (const float*)d_in[4];
  const float* Np   = (const float*)d_in[5];
  const float* w    = (const float*)d_in[6];
  const float* asrc = (const float*)d_in[7];
  const float* adst = (const float*)d_in[8];
  const float* bias = (const float*)d_in[9];
  float* out = (float*)d_out;

  char* ws = (char*)d_ws;
  unsigned short* wfrag = (unsigned short*)ws;                     // 256 KB
  unsigned short* hT    = (unsigned short*)(ws + 262144);          // 8 MB
  float* Rt    = (float*)(ws + 8650752);                           // 256 KB
  float* expd  = (float*)(ws + 8912896);                           // 256 KB
  float* expd2 = (float*)(ws + 9175040);                           // 256 KB
  unsigned long long* Abits = (unsigned long long*)(ws + 9437184); // 1 MB
  float* hpart = (float*)(ws + 10485760);                          // 16.8 MB

  stage0<<<dim3(1024), dim3(256), 0, stream>>>(w, A, wfrag, Abits);
  stageA<<<dim3(64, 8), dim3(512), 0, stream>>>(x, e_at, Np, wfrag, asrc, adst,
                                                hT, Rt, expd, expd2);
  stageB<<<dim3(1024), dim3(256), 0, stream>>>((const unsigned*)Abits, hT,
                                               Rt, expd, expd2, hpart);
  stageC<<<dim3(512), dim3(256), 0, stream>>>(hpart, bias, mz, out);
}

// Round 5
// 151.270 us; speedup vs baseline: 2.1535x; 1.0115x over previous
//
#include <hip/hip_runtime.h>

typedef __attribute__((ext_vector_type(8))) short          bf16x8;
typedef __attribute__((ext_vector_type(8))) unsigned short u16x8;
typedef __attribute__((ext_vector_type(4))) unsigned short u16x4;
typedef __attribute__((ext_vector_type(4))) float          f32x4;
typedef __attribute__((ext_vector_type(4))) unsigned int   u32x4;

union U8 { u16x8 u; bf16x8 b; u32x4 w; };
union U4 { u16x4 u; unsigned w[2]; };

__device__ __forceinline__ unsigned short f2bf(float f){
  unsigned u = __float_as_uint(f);
  return (unsigned short)((u + 0x7fffu + ((u >> 16) & 1u)) >> 16);
}
// pack two floats to bf16x2 (round-half-up): lo->low16, hi->high16. exact 0 preserved.
__device__ __forceinline__ unsigned pack_bf16(float lo, float hi){
  unsigned a = __float_as_uint(hi) + 0x8000u;
  unsigned b = __float_as_uint(lo) + 0x8000u;
  return __builtin_amdgcn_perm(a, b, 0x07060302u);
}
// max-pair -> packed bf16 (RNE) -> halfword mask (0xFFFF/0x0000 halves).
__device__ __forceinline__ unsigned maskpack(float e0, float e1, unsigned m){
  unsigned r;
  asm("v_cvt_pk_bf16_f32 %0, %1, %2" : "=v"(r) : "v"(e0), "v"(e1));
  return r & m;
}

#define NN  1024
#define FIN 256
#define NH  8
#define FO  64

// ---------------------------------------------------------------------------
// Stage 0: wfrag = w in MFMA-B-frag layout only (A bit-pack moved into stageA
// tail so its 33.5MB read overlaps stageA's latency-bound compute).
// grid 64 x 256 = 16384 threads.
// ---------------------------------------------------------------------------
__global__ __launch_bounds__(256) void stage0(
    const float* __restrict__ w, unsigned short* __restrict__ wfrag)
{
  const int tid = blockIdx.x * 256 + threadIdx.x;
  const int lane = tid & 63, ss = (tid >> 6) & 3, kc = (tid >> 8) & 7, h = tid >> 11;
  const int o = 16 * ss + (lane & 15);
  const int f = kc * 32 + (lane >> 4) * 8;
  u16x8 r;
  #pragma unroll
  for (int j = 0; j < 8; j++) r[j] = f2bf(w[(h * FIN + f + j) * FO + o]);
  *(u16x8*)(wfrag + tid * 8) = r;
}

// ---------------------------------------------------------------------------
// Stage A: recx built in LDS per 16-row tile; h = recx @ w (MFMA);
// panel stores hT[b,h,mtile,o,32] + exp tables (R = exp(0.8 s), Ed, Ed2).
// grid (64 tiles(16 rows), 8 b) = 512 blocks, block 512 (8 waves = 8 heads).
// Tail: each block bit-packs 1/512th of A (16384 ints) -> Abits for stageB.
// ---------------------------------------------------------------------------
__global__ __launch_bounds__(512, 4) void stageA(
    const float* __restrict__ x, const float* __restrict__ e_at,
    const float* __restrict__ Np, const unsigned short* __restrict__ wfrag,
    const float* __restrict__ a_src, const float* __restrict__ a_dst,
    const int* __restrict__ A, unsigned long long* __restrict__ Abits,
    unsigned short* __restrict__ hT,
    float* __restrict__ Rt, float* __restrict__ expd, float* __restrict__ expd2)
{
  __shared__ unsigned short rex[16 * 264];   // 16 rows x 256 f, pad 264
  const int t = threadIdx.x;
  const int n0 = blockIdx.x * 16, b = blockIdx.y;

  {                                          // cooperative recx tile build
    const int row = t >> 5, f0 = (t & 31) * 8;
    const int nrow = n0 + row;
    const float* ep = e_at + (b * NN + nrow) * FIN + f0;
    const float* qp = Np + nrow * FIN + f0;
    const float* xp = x + b * FIN + f0;
    f32x4 e0 = *(const f32x4*)ep, e1 = *(const f32x4*)(ep + 4);
    f32x4 q0 = *(const f32x4*)qp, q1 = *(const f32x4*)(qp + 4);
    f32x4 x0 = *(const f32x4*)xp, x1 = *(const f32x4*)(xp + 4);
    u16x8 r;
    #pragma unroll
    for (int j = 0; j < 4; j++){
      r[j]     = f2bf(e0[j] * q0[j] * x0[j]);
      r[j + 4] = f2bf(e1[j] * q1[j] * x1[j]);
    }
    *(u16x8*)(rex + row * 264 + f0) = r;
  }
  __syncthreads();

  const int h = t >> 6, lane = t & 63, quad = lane >> 4, l15 = lane & 15;
  const unsigned short* wf = wfrag + h * 16384 + lane * 8;

  f32x4 acc[4] = {};
  #pragma unroll
  for (int kc = 0; kc < 8; kc++){
    U8 a0, bf[4];
    a0.u = *(const u16x8*)(rex + l15 * 264 + kc * 32 + quad * 8);
    #pragma unroll
    for (int ss = 0; ss < 4; ss++) bf[ss].u = *(const u16x8*)(wf + (kc * 4 + ss) * 512);
    #pragma unroll
    for (int ss = 0; ss < 4; ss++)
      acc[ss] = __builtin_amdgcn_mfma_f32_16x16x32_bf16(a0.b, bf[ss].b, acc[ss], 0, 0, 0);
  }

  // panel store: [b,h,mtile,o(64),m(32)], C/D row(n)=quad*4+i, col(o)=16ss+l15
  {
    const int mtile = blockIdx.x >> 1, moff = (blockIdx.x & 1) * 16;
    unsigned short* pan = hT + (size_t)(((b * NH + h) * 32 + mtile) * 64) * 32;
    #pragma unroll
    for (int ss = 0; ss < 4; ss++){
      U4 v;
      v.w[0] = pack_bf16(acc[ss][0], acc[ss][1]);
      v.w[1] = pack_bf16(acc[ss][2], acc[ss][3]);
      *(u16x4*)(pan + (16 * ss + l15) * 32 + moff + quad * 4) = v.u;
    }
  }

  // s/d reductions -> exp tables (R = exp(0.8 s): row factor exp(0.2 s) cancels
  // in softmax, so P' = max(R*Ed, Ed2) gives identical attention weights)
  float as4[4], ad4[4];
  #pragma unroll
  for (int ss = 0; ss < 4; ss++){
    as4[ss] = a_src[h * FO + 16 * ss + l15];
    ad4[ss] = a_dst[h * FO + 16 * ss + l15];
  }
  #pragma unroll
  for (int i = 0; i < 4; i++){
    float ps = 0.f, pd = 0.f;
    #pragma unroll
    for (int ss = 0; ss < 4; ss++){ ps += acc[ss][i] * as4[ss]; pd += acc[ss][i] * ad4[ss]; }
    #pragma unroll
    for (int off = 1; off < 16; off <<= 1){
      ps += __shfl_xor(ps, off);
      pd += __shfl_xor(pd, off);
    }
    if (l15 == 0){
      const int idx = (b * NH + h) * NN + n0 + quad * 4 + i;
      Rt[idx]    = __expf(0.8f * ps);
      expd[idx]  = __expf(pd);
      expd2[idx] = __expf(0.2f * pd);
    }
  }

  // tail: adjacency bit-pack, 1/512th of A per block (overlaps other blocks'
  // compute; stageB is the only consumer)
  {
    const int seg = (b * 64 + blockIdx.x) * 16384;   // int base
    #pragma unroll 4
    for (int k = 0; k < 32; k++){
      const int i = seg + k * 512 + t;
      unsigned long long m = __ballot(A[i] > 0);
      if ((t & 63) == 0) Abits[i >> 6] = m;
    }
  }
}

// ---------------------------------------------------------------------------
// Stage B: fused masked-softmax aggregation, ZERO atomics, software-pipelined.
// 1024 flat blocks of 256 thr; block = 1 head x 64 rows; 4 waves =
// 2 row-halves(rw) x 2 m-halves(mh); each wave: 32 rows (2 row-groups
// in-register) x 512 cols, 16 fully-unrolled iters with cur/next register
// rotation: pan + mask prefetch for iter N+1 issues at the TOP of iter N,
// so the ~300cy L2 latency overlaps a full iteration of VALU+MFMA+LDS
// (R4 issued it at the bottom -> ~every iter stalled on vmcnt).
// __launch_bounds__(256,4): 128 reg/wave budget (R3 lesson: (256,8) spills).
// XCD decode b=fid&7: panels+Abits+tables L2-resident (R2: FETCH 43->5MB).
// m-halves merge through LDS; denominators per-wave LDS slots; mh=0 waves
// normalize and store per-head hpart coalesced. Head-merge in stageC.
// ---------------------------------------------------------------------------
__global__ __launch_bounds__(256, 4) void stageB(
    const unsigned* __restrict__ Aw,
    const unsigned short* __restrict__ hT,
    const float* __restrict__ Rt,
    const float* __restrict__ expd, const float* __restrict__ expd2,
    float* __restrict__ hpart)
{
  // phase 1: smem[0..1023]=Ed, [1024..2047]=Ed2 (this head)
  // phase 2: smem[0..4159]=merge[64][65], smem[4160..4287]=den[2mh][64]
  __shared__ float smem[4288];
  __shared__ __align__(8) unsigned lut[16][2];   // nibble -> 2 halfword masks

  const int fid = blockIdx.x;
  const int b = fid & 7, h = (fid >> 3) & 7, rt = fid >> 6;  // rt in [0,16)
  const int n0 = rt * 64;

  const int t = threadIdx.x;                     // 256
  const int w = t >> 6, lane = t & 63, quad = lane >> 4, l15 = lane & 15;
  const int rw = w & 1, mh = w >> 1;
  const int nb = n0 + rw * 32;                   // wave's 32-row base

  if (t < 16){
    lut[t][0] = (t & 1 ? 0xFFFFu : 0u) | (t & 2 ? 0xFFFF0000u : 0u);
    lut[t][1] = (t & 4 ? 0xFFFFu : 0u) | (t & 8 ? 0xFFFF0000u : 0u);
  }
  {                                      // exp-table preload (1 head, coalesced)
    const float* s1 = expd  + (b * NH + h) * NN;
    const float* s2 = expd2 + (b * NH + h) * NN;
    *(f32x4*)(smem + t * 4)        = *(const f32x4*)(s1 + t * 4);
    *(f32x4*)(smem + 1024 + t * 4) = *(const f32x4*)(s2 + t * 4);
  }
  __syncthreads();

  const int hb = (b * NH + h) * NN;
  const float Rv0 = Rt[hb + nb + l15];
  const float Rv1 = Rt[hb + nb + 16 + l15];
  const unsigned short* pb = hT + (size_t)(b * NH + h) * 65536 + l15 * 32 + quad * 8;
  const float* edh = smem + quad * 8;
  const float* e2h = smem + 1024 + quad * 8;
  const unsigned* awp = Aw + (b * NN + nb) * 32;
  const int c0 = mh * 16;
  const int qs = quad * 8;

  // pipeline prologue: iter 0's pan frags + mask words
  U8 panc[4], pann[4];
  #pragma unroll
  for (int ss = 0; ss < 4; ss++)
    panc[ss].u = *(const u16x8*)(pb + (size_t)c0 * 2048 + ss * 512);
  unsigned mwc0 = awp[l15 * 32 + c0];
  unsigned mwc1 = awp[(16 + l15) * 32 + c0];
  unsigned mwn0, mwn1;

  U8 ones;                               // bf16 1.0 B-frag for row sums
  #pragma unroll
  for (int j = 0; j < 8; j++) ones.u[j] = 0x3F80;

  f32x4 acc0[4] = {}, acc1[4] = {};
  f32x4 accl0 = {}, accl1 = {};

  #pragma unroll
  for (int cc = 0; cc < 16; cc++){
    const int c = c0 + cc;
    // --- prefetch iter N+1 FIRST (L2 latency overlaps this whole iter) ---
    if (cc + 1 < 16){
      #pragma unroll
      for (int ss = 0; ss < 4; ss++)
        pann[ss].u = *(const u16x8*)(pb + (size_t)(c + 1) * 2048 + ss * 512);
      mwn0 = awp[l15 * 32 + c + 1];
      mwn1 = awp[(16 + l15) * 32 + c + 1];
    }
    // expand bit masks via LUT (mask words from previous iter's prefetch)
    const unsigned am0 = (mwc0 >> qs) & 0xFF;
    const unsigned am1 = (mwc1 >> qs) & 0xFF;
    const uint2 la0 = *(const uint2*)&lut[am0 & 15][0];
    const uint2 lb0 = *(const uint2*)&lut[(am0 >> 4) & 15][0];
    const uint2 la1 = *(const uint2*)&lut[am1 & 15][0];
    const uint2 lb1 = *(const uint2*)&lut[(am1 >> 4) & 15][0];
    // shared column factors (broadcast LDS reads, conflict-free)
    const f32x4 d01 = *(const f32x4*)(edh + c * 32);
    const f32x4 d23 = *(const f32x4*)(edh + c * 32 + 4);
    const f32x4 g01 = *(const f32x4*)(e2h + c * 32);
    const f32x4 g23 = *(const f32x4*)(e2h + c * 32 + 4);
    // P for row-group 0
    {
      const f32x4 p01 = Rv0 * d01, p23 = Rv0 * d23;
      U8 p;
      p.w[0] = maskpack(fmaxf(p01[0], g01[0]), fmaxf(p01[1], g01[1]), la0.x);
      p.w[1] = maskpack(fmaxf(p01[2], g01[2]), fmaxf(p01[3], g01[3]), la0.y);
      p.w[2] = maskpack(fmaxf(p23[0], g23[0]), fmaxf(p23[1], g23[1]), lb0.x);
      p.w[3] = maskpack(fmaxf(p23[2], g23[2]), fmaxf(p23[3], g23[3]), lb0.y);
      #pragma unroll
      for (int ss = 0; ss < 4; ss++)
        acc0[ss] = __builtin_amdgcn_mfma_f32_16x16x32_bf16(p.b, panc[ss].b, acc0[ss], 0, 0, 0);
      accl0 = __builtin_amdgcn_mfma_f32_16x16x32_bf16(p.b, ones.b, accl0, 0, 0, 0);
    }
    // P for row-group 1 (same pan frags -> panel traffic halved)
    {
      const f32x4 p01 = Rv1 * d01, p23 = Rv1 * d23;
      U8 p;
      p.w[0] = maskpack(fmaxf(p01[0], g01[0]), fmaxf(p01[1], g01[1]), la1.x);
      p.w[1] = maskpack(fmaxf(p01[2], g01[2]), fmaxf(p01[3], g01[3]), la1.y);
      p.w[2] = maskpack(fmaxf(p23[0], g23[0]), fmaxf(p23[1], g23[1]), lb1.x);
      p.w[3] = maskpack(fmaxf(p23[2], g23[2]), fmaxf(p23[3], g23[3]), lb1.y);
      #pragma unroll
      for (int ss = 0; ss < 4; ss++)
        acc1[ss] = __builtin_amdgcn_mfma_f32_16x16x32_bf16(p.b, panc[ss].b, acc1[ss], 0, 0, 0);
      accl1 = __builtin_amdgcn_mfma_f32_16x16x32_bf16(p.b, ones.b, accl1, 0, 0, 0);
    }
    // rotate (vanishes under full unroll via renaming)
    if (cc + 1 < 16){
      #pragma unroll
      for (int ss = 0; ss < 4; ss++) panc[ss] = pann[ss];
      mwc0 = mwn0; mwc1 = mwn1;
    }
  }

  __syncthreads();                       // tables dead; smem becomes merge buffer

  // denominators: accl[i] = complete row sum over this wave's m-half,
  // replicated over l15. Distinct (mh,rw,row) slots -> no atomics.
  float* den = smem + 4160;
  if (l15 == 0){
    #pragma unroll
    for (int i = 0; i < 4; i++){
      den[mh * 64 + rw * 32 + quad * 4 + i]      = accl0[i];
      den[mh * 64 + rw * 32 + 16 + quad * 4 + i] = accl1[i];
    }
  }
  // mh=1 waves park their numerators in merge[64][65]
  if (mh == 1){
    #pragma unroll
    for (int i = 0; i < 4; i++){
      const int r0 = rw * 32 + quad * 4 + i;
      #pragma unroll
      for (int ss = 0; ss < 4; ss++){
        smem[r0 * 65 + ss * 16 + l15]        = acc0[ss][i];
        smem[(r0 + 16) * 65 + ss * 16 + l15] = acc1[ss][i];
      }
    }
  }
  __syncthreads();

  // mh=0 waves: add halves, normalize, plain coalesced store to hpart
  if (mh == 0){
    float* hp = hpart + ((size_t)(b * NH + h) * NN + nb) * FO;
    #pragma unroll
    for (int i = 0; i < 4; i++){
      const int r = quad * 4 + i;
      const float ia = 1.0f / (den[rw * 32 + r] + den[64 + rw * 32 + r]);
      const float ib = 1.0f / (den[rw * 32 + 16 + r] + den[64 + rw * 32 + 16 + r]);
      #pragma unroll
      for (int ss = 0; ss < 4; ss++){
        hp[(size_t)r * FO + ss * 16 + l15] =
            (acc0[ss][i] + smem[(rw * 32 + r) * 65 + ss * 16 + l15]) * ia;
        hp[(size_t)(16 + r) * FO + ss * 16 + l15] =
            (acc1[ss][i] + smem[(rw * 32 + 16 + r) * 65 + ss * 16 + l15]) * ib;
      }
    }
  }
}

// ---------------------------------------------------------------------------
// Stage C: head mean + bias + mask. out = (0.125*sum_h hpart + bias) * mz.
// 16.8 MB streamed reads, 2 MB writes. grid 512 x 256, 4 outputs/thread.
// ---------------------------------------------------------------------------
__global__ __launch_bounds__(256) void stageC(
    const float* __restrict__ hpart, const float* __restrict__ bias,
    const float* __restrict__ mz, float* __restrict__ out)
{
  const int tid = blockIdx.x * 256 + threadIdx.x;    // 131072 threads
  const int o4 = (tid & 15) * 4;
  const int n  = (tid >> 4) & 1023;
  const int b  = tid >> 14;
  const size_t nf = (size_t)n * FO + o4;
  f32x4 s = {};
  #pragma unroll
  for (int h = 0; h < NH; h++)
    s += *(const f32x4*)(hpart + (size_t)(b * NH + h) * NN * FO + nf);
  const f32x4 bv = *(const f32x4*)(bias + o4);
  const float m = mz[b * NN + n];
  f32x4 r;
  #pragma unroll
  for (int j = 0; j < 4; j++) r[j] = (0.125f * s[j] + bv[j]) * m;
  *(f32x4*)(out + (size_t)b * NN * FO + nf) = r;
}

extern "C" void kernel_launch(void* const* d_in, const int* in_sizes, int n_in,
                              void* d_out, int out_size, void* d_ws, size_t ws_size,
                              hipStream_t stream)
{
  (void)in_sizes; (void)n_in; (void)out_size; (void)ws_size;
  const float* x    = (const float*)d_in[0];
  const int*   A    = (const int*)d_in[1];
  const float* mz   = (const float*)d_in[2];
  const float* e_at = (const float*)d_in[4];
  const float* Np   = (const float*)d_in[5];
  const float* w    = (const float*)d_in[6];
  const float* asrc = (const float*)d_in[7];
  const float* adst = (const float*)d_in[8];
  const float* bias = (const float*)d_in[9];
  float* out = (float*)d_out;

  char* ws = (char*)d_ws;
  unsigned short* wfrag = (unsigned short*)ws;                     // 256 KB
  unsigned short* hT    = (unsigned short*)(ws + 262144);          // 8 MB
  float* Rt    = (float*)(ws + 8650752);                           // 256 KB
  float* expd  = (float*)(ws + 8912896);                           // 256 KB
  float* expd2 = (float*)(ws + 9175040);                           // 256 KB
  unsigned long long* Abits = (unsigned long long*)(ws + 9437184); // 1 MB
  float* hpart = (float*)(ws + 10485760);                          // 16.8 MB

  stage0<<<dim3(64), dim3(256), 0, stream>>>(w, wfrag);
  stageA<<<dim3(64, 8), dim3(512), 0, stream>>>(x, e_at, Np, wfrag, asrc, adst,
                                                A, Abits, hT, Rt, expd, expd2);
  stageB<<<dim3(1024), dim3(256), 0, stream>>>((const unsigned*)Abits, hT,
                                               Rt, expd, expd2, hpart);
  stageC<<<dim3(512), dim3(256), 0, stream>>>(hpart, bias, mz, out);
}